// Round 19
// baseline (296.849 us; speedup 1.0000x reference)
//
#include <hip/hip_runtime.h>
#include <hip/hip_bf16.h>
#include <math.h>

typedef __attribute__((ext_vector_type(8))) short bf16x8;
typedef __attribute__((ext_vector_type(4))) float f32x4;

__device__ inline ushort f2bf(float f) {
    uint u = __float_as_uint(f);
    uint r = u + 0x7fffu + ((u >> 16) & 1u);
    return (ushort)(r >> 16);
}
__device__ inline float bf2f(ushort h) { return __uint_as_float(((uint)h) << 16); }

// gelu tanh-approx via sigmoid identity: 0.5x(1+tanh(z)) = x/(1+exp(-2z))
__device__ inline float gelu_fast(float x) {
    float z2 = 1.5957691216057308f * (x + 0.044715f * x * x * x);
    return x / (1.0f + __expf(-z2));
}

// ---------------- pass 1: degree histogram + rank, merged with weight packing ----------------

__global__ void pass1_kernel(const int* __restrict__ col, int* __restrict__ deg64,
                             int* __restrict__ rank, int E,
                             const float* __restrict__ W1, const float* __restrict__ W2,
                             ushort* __restrict__ p1, ushort* __restrict__ p2) {
    int nbE = (E + 255) >> 8;
    int b = blockIdx.x;
    if (b < nbE) {
        int e = b * 256 + threadIdx.x;
        if (e < E) rank[e] = atomicAdd(&deg64[col[e] << 4], 1);
        return;
    }
    int u = (b - nbE) * 256 + threadIdx.x;
    if (u < 4096) {                      // W1 pack: g = B*4 + ks (B = oc-block)
        int g = u >> 6, l = u & 63;
        int B = g >> 2, ks = g & 3;
        int oc = B * 16 + (l & 15);
        int kb = ks * 32 + (l >> 4) * 8;
        ushort tmp[8];
        #pragma unroll
        for (int j = 0; j < 8; ++j) tmp[j] = f2bf(W1[(size_t)(kb + j) * 256 + oc]);
        *(bf16x8*)(p1 + (size_t)u * 8) = *(bf16x8*)tmp;
    } else if (u < 8192) {               // W2 pack: g = B*8 + ks
        int v = u - 4096;
        int g = v >> 6, l = v & 63;
        int B = g >> 3, ks = g & 7;
        int oc = B * 16 + (l & 15);
        int kb = ks * 32 + (l >> 4) * 8;
        ushort tmp[8];
        #pragma unroll
        for (int j = 0; j < 8; ++j) tmp[j] = f2bf(W2[(size_t)(kb + j) * 128 + oc]);
        *(bf16x8*)(p2 + (size_t)v * 8) = *(bf16x8*)tmp;
    }
}

// merged: dinv + compact deg + per-block sums
__global__ void dinv_reduce_kernel(const int* __restrict__ deg64, float* __restrict__ dinv,
                                   int* __restrict__ deg, int* __restrict__ bsum, int M) {
    __shared__ int s[256];
    int i = blockIdx.x * 256 + threadIdx.x;
    int d = 0;
    if (i < M) {
        d = deg64[i << 4];
        deg[i] = d;
        dinv[i] = rsqrtf((float)d + 1.0f);   // +1 self loop
    }
    s[threadIdx.x] = d;
    __syncthreads();
    for (int o = 128; o > 0; o >>= 1) {
        if (threadIdx.x < o) s[threadIdx.x] += s[threadIdx.x + o];
        __syncthreads();
    }
    if (threadIdx.x == 0) bsum[blockIdx.x] = s[0];
}

__global__ void scan_bsum_kernel(int* __restrict__ bsum, int nb) {
    __shared__ int s[512];
    int t = threadIdx.x;
    int orig = (t < nb) ? bsum[t] : 0;
    s[t] = orig;
    __syncthreads();
    for (int o = 1; o < 512; o <<= 1) {
        int v = 0;
        if (t >= o) v = s[t - o];
        __syncthreads();
        if (t >= o) s[t] += v;
        __syncthreads();
    }
    if (t < nb) bsum[t] = s[t] - orig;  // exclusive
}

__global__ void scan_offsets_kernel(const int* __restrict__ deg, const int* __restrict__ bsum,
                                    int* __restrict__ off, int M) {
    __shared__ int s[256];
    int i = blockIdx.x * 256 + threadIdx.x;
    int orig = (i < M) ? deg[i] : 0;
    s[threadIdx.x] = orig;
    __syncthreads();
    for (int o = 1; o < 256; o <<= 1) {
        int v = 0;
        if (threadIdx.x >= o) v = s[threadIdx.x - o];
        __syncthreads();
        if (threadIdx.x >= o) s[threadIdx.x] += v;
        __syncthreads();
    }
    if (i < M) off[i] = bsum[blockIdx.x] + s[threadIdx.x] - orig;  // exclusive
}

// ---------------- pass 2: atomic-free CSR scatter + xb conversion ----------------

__global__ void pass2_kernel(const int* __restrict__ row, const int* __restrict__ col,
                             const int* __restrict__ off, const int* __restrict__ rank,
                             int* __restrict__ rs, int E,
                             const float* __restrict__ x, const float* __restrict__ dinv,
                             ushort* __restrict__ xb, int n8) {
    int nbE = (E + 255) >> 8;
    int b = blockIdx.x;
    if (b < nbE) {
        int e = b * 256 + threadIdx.x;
        if (e < E) rs[off[col[e]] + rank[e]] = row[e];
        return;
    }
    int i = (b - nbE) * 256 + threadIdx.x;
    if (i < n8) {
        float s = dinv[i >> 4];
        float4 a = *(const float4*)(x + (size_t)i * 8);
        float4 v = *(const float4*)(x + (size_t)i * 8 + 4);
        ushort4 u0 = make_ushort4(f2bf(a.x * s), f2bf(a.y * s), f2bf(a.z * s), f2bf(a.w * s));
        ushort4 u1 = make_ushort4(f2bf(v.x * s), f2bf(v.y * s), f2bf(v.z * s), f2bf(v.w * s));
        *(ushort4*)(xb + (size_t)i * 8) = u0;
        *(ushort4*)(xb + (size_t)i * 8 + 4) = u1;
    }
}

// ---------------- fused MLP v6: 128 rows/block, 8 waves, packed weights ----------------
// Swapped-operand MFMA (C: node = lane&15, outcol = lk*4+reg).
// gemm1: wave w covers oc-blocks {2w,2w+1}; gemm2: wave w covers oc-block w.
// Each weight fragment feeds 8 MFMAs (m-tiles); weight traffic halved vs v5.

__global__ __launch_bounds__(512, 2) void gemm_fused(const ushort* __restrict__ A,
                                                     const ushort* __restrict__ p1,
                                                     const float* __restrict__ b1,
                                                     const ushort* __restrict__ p2,
                                                     const float* __restrict__ dinv,
                                                     ushort* __restrict__ Cb, int M) {
    __shared__ ushort la[128 * 128];   // A tile, 32KB (row-XOR swizzled)
    __shared__ ushort lh[128 * 256];   // h tile, 64KB (row-XOR swizzled)

    const int t = threadIdx.x;
    const int R0 = blockIdx.x * 128;
    const int w = t >> 6, l = t & 63;
    const int lrow = l & 15;
    const int lk = l >> 4;

    // ---- stage A tile: 2048 chunks / 512 threads, coalesced ----
    #pragma unroll
    for (int base = 0; base < 2048; base += 512) {
        int idx = base + t;
        int r = idx >> 4;
        int c8 = idx & 15;
        int gr = R0 + r;
        gr = gr < M ? gr : M - 1;                    // clamp (tail block)
        bf16x8 v = *(const bf16x8*)(A + (size_t)gr * 128 + c8 * 8);
        int byte = idx * 16 ^ ((r & 7) << 4);        // swizzled write
        *(bf16x8*)((char*)la + byte) = v;
    }

    // ---- hoist W1 fragments (oc-blocks 2w, 2w+1) ----
    bf16x8 w1[2][4];
    #pragma unroll
    for (int n = 0; n < 2; ++n)
        #pragma unroll
        for (int ks = 0; ks < 4; ++ks)
            w1[n][ks] = *(const bf16x8*)(p1 + (size_t)((((w * 2 + n) * 4 + ks) * 64 + l) * 8));
    __syncthreads();

    // ---- gemm1: LDS A + register W, 8 m-tiles ----
    {
        const int c0 = w * 32;
        f32x4 acc[2][8] = {};
        #pragma unroll
        for (int ks = 0; ks < 4; ++ks) {
            bf16x8 xf[8];
            #pragma unroll
            for (int m = 0; m < 8; ++m) {
                int nd = m * 16 + lrow;
                int byte = (nd * 256 + ks * 64 + lk * 16) ^ ((nd & 7) << 4);
                xf[m] = *(const bf16x8*)((const char*)la + byte);
            }
            #pragma unroll
            for (int n = 0; n < 2; ++n)
                #pragma unroll
                for (int m = 0; m < 8; ++m)
                    acc[n][m] = __builtin_amdgcn_mfma_f32_16x16x32_bf16(w1[n][ks], xf[m], acc[n][m], 0, 0, 0);
        }
        // epilogue1: gelu(v+b1) -> packed 8B LDS stores
        #pragma unroll
        for (int n = 0; n < 2; ++n) {
            int ob = c0 + n * 16 + lk * 4;
            float4 bb = *(const float4*)(b1 + ob);
            #pragma unroll
            for (int m = 0; m < 8; ++m) {
                int nd = m * 16 + lrow;
                ushort4 pk;
                pk.x = f2bf(gelu_fast(acc[n][m][0] + bb.x));
                pk.y = f2bf(gelu_fast(acc[n][m][1] + bb.y));
                pk.z = f2bf(gelu_fast(acc[n][m][2] + bb.z));
                pk.w = f2bf(gelu_fast(acc[n][m][3] + bb.w));
                int byte = (nd * 256 + ob) * 2;
                byte ^= (nd & 7) << 4;
                *(ushort4*)((char*)lh + byte) = pk;
            }
        }
    }

    // ---- hoist W2 fragments (oc-block w) ----
    bf16x8 w2[8];
    #pragma unroll
    for (int ks = 0; ks < 8; ++ks)
        w2[ks] = *(const bf16x8*)(p2 + (size_t)(((w * 8 + ks) * 64 + l) * 8));
    __syncthreads();

    // ---- gemm2: LDS h + register W, 8 m-tiles ----
    {
        const int c0 = w * 16;
        f32x4 acc2[8] = {};
        #pragma unroll
        for (int ks = 0; ks < 8; ++ks) {
            const int kb = ks * 32 + lk * 8;
            bf16x8 hf[8];
            #pragma unroll
            for (int m = 0; m < 8; ++m) {
                int nd = m * 16 + lrow;
                int byte = (nd * 256 + kb) * 2;
                byte ^= (nd & 7) << 4;
                hf[m] = *(const bf16x8*)((const char*)lh + byte);
            }
            #pragma unroll
            for (int m = 0; m < 8; ++m)
                acc2[m] = __builtin_amdgcn_mfma_f32_16x16x32_bf16(w2[ks], hf[m], acc2[m], 0, 0, 0);
        }
        // epilogue2: dinv-scaled bf16, packed 8B global stores (in place)
        #pragma unroll
        for (int m = 0; m < 8; ++m) {
            int nd = m * 16 + lrow;
            int grow = R0 + nd;
            if (grow < M) {
                float sc = dinv[grow];
                int ob = c0 + lk * 4;
                ushort4 pk;
                pk.x = f2bf(acc2[m][0] * sc);
                pk.y = f2bf(acc2[m][1] * sc);
                pk.z = f2bf(acc2[m][2] * sc);
                pk.w = f2bf(acc2[m][3] * sc);
                *(ushort4*)(Cb + (size_t)grow * 128 + ob) = pk;
            }
        }
    }
}

// ---------------- segment-sum gather, 16 edges in flight ----------------

template <bool BIAS, bool OUTBF>
__global__ __launch_bounds__(256) void gather_sum_kernel(const int* __restrict__ off,
                                                         const int* __restrict__ deg,
                                                         const int* __restrict__ rs,
                                                         const float* __restrict__ dinv,
                                                         const ushort* __restrict__ srcb,
                                                         const float* __restrict__ b,
                                                         float* __restrict__ dstf,
                                                         ushort* __restrict__ dstb, int M) {
    int wid = (blockIdx.x * 256 + threadIdx.x) >> 6;
    int lane = threadIdx.x & 63;
    int grp = lane >> 4;
    int l16 = lane & 15;
    if (wid >= M) return;
    int s0 = off[wid];
    int n = deg[wid];
    float acc[8] = {};
    float acc2[8] = {};

    if (grp == 0) {
        bf16x8 u = *(const bf16x8*)(srcb + (size_t)wid * 128 + l16 * 8);
        #pragma unroll
        for (int i = 0; i < 8; ++i) acc[i] += bf2f((ushort)u[i]);
    }

    int j = 0;
    for (; j + 16 <= n; j += 16) {
        int r0 = rs[s0 + j + grp];
        int r1 = rs[s0 + j + 4 + grp];
        int r2 = rs[s0 + j + 8 + grp];
        int r3 = rs[s0 + j + 12 + grp];
        bf16x8 u0 = *(const bf16x8*)(srcb + (size_t)r0 * 128 + l16 * 8);
        bf16x8 u1 = *(const bf16x8*)(srcb + (size_t)r1 * 128 + l16 * 8);
        bf16x8 u2 = *(const bf16x8*)(srcb + (size_t)r2 * 128 + l16 * 8);
        bf16x8 u3 = *(const bf16x8*)(srcb + (size_t)r3 * 128 + l16 * 8);
        #pragma unroll
        for (int i = 0; i < 8; ++i) {
            acc[i] += bf2f((ushort)u0[i]) + bf2f((ushort)u2[i]);
            acc2[i] += bf2f((ushort)u1[i]) + bf2f((ushort)u3[i]);
        }
    }
    for (; j + 4 <= n; j += 4) {
        int r = rs[s0 + j + grp];
        bf16x8 u = *(const bf16x8*)(srcb + (size_t)r * 128 + l16 * 8);
        #pragma unroll
        for (int i = 0; i < 8; ++i) acc[i] += bf2f((ushort)u[i]);
    }
    if (j + grp < n) {
        int r = rs[s0 + j + grp];
        bf16x8 u = *(const bf16x8*)(srcb + (size_t)r * 128 + l16 * 8);
        #pragma unroll
        for (int i = 0; i < 8; ++i) acc2[i] += bf2f((ushort)u[i]);
    }

    #pragma unroll
    for (int i = 0; i < 8; ++i) {
        acc[i] += acc2[i];
        acc[i] += __shfl_xor(acc[i], 16);
        acc[i] += __shfl_xor(acc[i], 32);
    }

    if (grp == 0) {
        float sc = dinv[wid];
        #pragma unroll
        for (int i = 0; i < 8; ++i) acc[i] *= sc;
        if constexpr (BIAS) {
            float4 b0 = *(const float4*)(b + l16 * 8);
            float4 b1v = *(const float4*)(b + l16 * 8 + 4);
            acc[0] += b0.x; acc[1] += b0.y; acc[2] += b0.z; acc[3] += b0.w;
            acc[4] += b1v.x; acc[5] += b1v.y; acc[6] += b1v.z; acc[7] += b1v.w;
        }
        if constexpr (OUTBF) {
            bf16x8 o;
            #pragma unroll
            for (int i = 0; i < 8; ++i) o[i] = (short)f2bf(acc[i]);
            *(bf16x8*)(dstb + (size_t)wid * 128 + l16 * 8) = o;
        } else {
            float4 o0 = make_float4(acc[0], acc[1], acc[2], acc[3]);
            float4 o1 = make_float4(acc[4], acc[5], acc[6], acc[7]);
            *(float4*)(dstf + (size_t)wid * 128 + l16 * 8) = o0;
            *(float4*)(dstf + (size_t)wid * 128 + l16 * 8 + 4) = o1;
        }
    }
}

// ---------------- launch ----------------

extern "C" void kernel_launch(void* const* d_in, const int* in_sizes, int n_in,
                              void* d_out, int out_size, void* d_ws, size_t ws_size,
                              hipStream_t stream) {
    const float* x  = (const float*)d_in[0];
    const int*   ei = (const int*)d_in[1];
    const float* W1 = (const float*)d_in[2];
    const float* b1 = (const float*)d_in[3];
    const float* W2 = (const float*)d_in[4];
    const float* b2 = (const float*)d_in[5];

    const int M = in_sizes[0] / 128;      // 100000
    const int E = in_sizes[1] / 2;        // 1600000
    const int* row = ei;
    const int* col = ei + E;

    // High-water ~73 MB.
    ushort* xb    = (ushort*)d_ws;              // 12,800,000 us (x*dinv, bf16)
    ushort* aggxb = xb + 12800000;              // 12,800,000 us [N,128]
    ushort* xw2b  = aggxb;                      // IN-PLACE alias (fused gemm same-row)
    float*  dinv  = (float*)(aggxb + 12800000); // 102,400 f
    int*    deg64 = (int*)(dinv + 102400);      // 1,638,400 i (64B-padded counters)
    int*    deg   = deg64 + 1638400;            // 102,400 i (compact, for scans)
    int*    off   = deg + 102400;               // 102,400 i
    int*    rank  = off + 102400;               // 1,600,000 i
    int*    rs    = rank + 1600000;             // 1,600,000 i
    int*    bsum  = rs + 1600000;               // 1,024 i
    ushort* p1    = (ushort*)(bsum + 1024);     // 32,768 us (W1 fragment-packed)
    ushort* p2    = p1 + 32768;                 // 32,768 us (W2 fragment-packed)
    float*  outw  = (float*)d_out;

    const int nb  = (M + 255) / 256;
    const int nbE = (E + 255) / 256;
    const int n8  = M * 16;

    hipMemsetAsync(deg64, 0, (size_t)1638400 * sizeof(int), stream);

    // pass 1: atomic histogram + rank, weight-pack riding the stall slots
    pass1_kernel<<<nbE + 32, 256, 0, stream>>>(col, deg64, rank, E, W1, W2, p1, p2);

    dinv_reduce_kernel<<<nb, 256, 0, stream>>>(deg64, dinv, deg, bsum, M);
    scan_bsum_kernel<<<1, 512, 0, stream>>>(bsum, nb);
    scan_offsets_kernel<<<nb, 256, 0, stream>>>(deg, bsum, off, M);

    // pass 2: CSR scatter + xb conversion riding the stall slots
    pass2_kernel<<<nbE + (n8 + 255) / 256, 256, 0, stream>>>(row, col, off, rank, rs, E,
                                                             x, dinv, xb, n8);

    // layer 1 aggregate (self from table), bf16 out
    gather_sum_kernel<false, true><<<(M * 64 + 255) / 256, 256, 0, stream>>>(
        off, deg, rs, dinv, xb, nullptr, nullptr, aggxb, M);

    // fused MLP: 128 rows/block, 8 waves, packed weights
    gemm_fused<<<(M + 127) / 128, 512, 0, stream>>>(aggxb, p1, b1, p2, dinv, xw2b, M);

    // layer 2 aggregate (self from table) + bias, fp32 out
    gather_sum_kernel<true, false><<<(M * 64 + 255) / 256, 256, 0, stream>>>(
        off, deg, rs, dinv, xw2b, b2, outw, nullptr, M);
}

// Round 20
// 278.324 us; speedup vs baseline: 1.0666x; 1.0666x over previous
//
#include <hip/hip_runtime.h>
#include <hip/hip_bf16.h>
#include <math.h>

typedef __attribute__((ext_vector_type(8))) short bf16x8;
typedef __attribute__((ext_vector_type(4))) float f32x4;

__device__ inline ushort f2bf(float f) {
    uint u = __float_as_uint(f);
    uint r = u + 0x7fffu + ((u >> 16) & 1u);
    return (ushort)(r >> 16);
}
__device__ inline float bf2f(ushort h) { return __uint_as_float(((uint)h) << 16); }

// gelu tanh-approx via sigmoid identity: 0.5x(1+tanh(z)) = x/(1+exp(-2z))
__device__ inline float gelu_fast(float x) {
    float z2 = 1.5957691216057308f * (x + 0.044715f * x * x * x);
    return x / (1.0f + __expf(-z2));
}

// ---------------- pass 1: degree histogram + rank, MERGED with weight packing ----------------
// The atomic kernel is stall-bound (VALUBusy 0.5%) -> co-resident packing
// blocks fill the idle issue slots for free. Counters 64B-padded (R15).

__global__ void pass1_kernel(const int* __restrict__ col, int* __restrict__ deg64,
                             int* __restrict__ rank, int E,
                             const float* __restrict__ W1, const float* __restrict__ W2,
                             ushort* __restrict__ p1, ushort* __restrict__ p2) {
    int nbE = (E + 255) >> 8;
    int b = blockIdx.x;
    if (b < nbE) {
        int e = b * 256 + threadIdx.x;
        if (e < E) rank[e] = atomicAdd(&deg64[col[e] << 4], 1);
        return;
    }
    int u = (b - nbE) * 256 + threadIdx.x;
    if (u < 4096) {                      // W1 pack: g = w*16 + n*4 + ks
        int g = u >> 6, l = u & 63;
        int w = g >> 4, n = (g >> 2) & 3, ks = g & 3;
        int oc = w * 64 + n * 16 + (l & 15);
        int kb = ks * 32 + (l >> 4) * 8;
        ushort tmp[8];
        #pragma unroll
        for (int j = 0; j < 8; ++j) tmp[j] = f2bf(W1[(size_t)(kb + j) * 256 + oc]);
        *(bf16x8*)(p1 + (size_t)u * 8) = *(bf16x8*)tmp;
    } else if (u < 8192) {               // W2 pack: g = w*16 + n*8 + ks
        int v = u - 4096;
        int g = v >> 6, l = v & 63;
        int w = g >> 4, n = (g >> 3) & 1, ks = g & 7;
        int oc = w * 32 + n * 16 + (l & 15);
        int kb = ks * 32 + (l >> 4) * 8;
        ushort tmp[8];
        #pragma unroll
        for (int j = 0; j < 8; ++j) tmp[j] = f2bf(W2[(size_t)(kb + j) * 128 + oc]);
        *(bf16x8*)(p2 + (size_t)v * 8) = *(bf16x8*)tmp;
    }
}

// merged: dinv + compact deg + per-block sums (one pass over counters)
__global__ void dinv_reduce_kernel(const int* __restrict__ deg64, float* __restrict__ dinv,
                                   int* __restrict__ deg, int* __restrict__ bsum, int M) {
    __shared__ int s[256];
    int i = blockIdx.x * 256 + threadIdx.x;
    int d = 0;
    if (i < M) {
        d = deg64[i << 4];
        deg[i] = d;
        dinv[i] = rsqrtf((float)d + 1.0f);   // +1 self loop
    }
    s[threadIdx.x] = d;
    __syncthreads();
    for (int o = 128; o > 0; o >>= 1) {
        if (threadIdx.x < o) s[threadIdx.x] += s[threadIdx.x + o];
        __syncthreads();
    }
    if (threadIdx.x == 0) bsum[blockIdx.x] = s[0];
}

__global__ void scan_bsum_kernel(int* __restrict__ bsum, int nb) {
    __shared__ int s[512];
    int t = threadIdx.x;
    int orig = (t < nb) ? bsum[t] : 0;
    s[t] = orig;
    __syncthreads();
    for (int o = 1; o < 512; o <<= 1) {
        int v = 0;
        if (t >= o) v = s[t - o];
        __syncthreads();
        if (t >= o) s[t] += v;
        __syncthreads();
    }
    if (t < nb) bsum[t] = s[t] - orig;  // exclusive
}

__global__ void scan_offsets_kernel(const int* __restrict__ deg, const int* __restrict__ bsum,
                                    int* __restrict__ off, int M) {
    __shared__ int s[256];
    int i = blockIdx.x * 256 + threadIdx.x;
    int orig = (i < M) ? deg[i] : 0;
    s[threadIdx.x] = orig;
    __syncthreads();
    for (int o = 1; o < 256; o <<= 1) {
        int v = 0;
        if (threadIdx.x >= o) v = s[threadIdx.x - o];
        __syncthreads();
        if (threadIdx.x >= o) s[threadIdx.x] += v;
        __syncthreads();
    }
    if (i < M) off[i] = bsum[blockIdx.x] + s[threadIdx.x] - orig;  // exclusive
}

// ---------------- pass 2: atomic-free CSR scatter, MERGED with xb conversion ----------------

__global__ void pass2_kernel(const int* __restrict__ row, const int* __restrict__ col,
                             const int* __restrict__ off, const int* __restrict__ rank,
                             int* __restrict__ rs, int E,
                             const float* __restrict__ x, const float* __restrict__ dinv,
                             ushort* __restrict__ xb, int n8) {
    int nbE = (E + 255) >> 8;
    int b = blockIdx.x;
    if (b < nbE) {
        int e = b * 256 + threadIdx.x;
        if (e < E) rs[off[col[e]] + rank[e]] = row[e];
        return;
    }
    int i = (b - nbE) * 256 + threadIdx.x;
    if (i < n8) {
        float s = dinv[i >> 4];
        float4 a = *(const float4*)(x + (size_t)i * 8);
        float4 v = *(const float4*)(x + (size_t)i * 8 + 4);
        ushort4 u0 = make_ushort4(f2bf(a.x * s), f2bf(a.y * s), f2bf(a.z * s), f2bf(a.w * s));
        ushort4 u1 = make_ushort4(f2bf(v.x * s), f2bf(v.y * s), f2bf(v.z * s), f2bf(v.w * s));
        *(ushort4*)(xb + (size_t)i * 8) = u0;
        *(ushort4*)(xb + (size_t)i * 8 + 4) = u1;
    }
}

// ---------------- fused MLP: coalesced packed weights + LDS-staged A ----------------
// 64 rows/block, swapped-operand MFMA (C: node = lane&15, outcol = lk*4+reg).

__global__ __launch_bounds__(256, 2) void gemm_fused(const ushort* __restrict__ A,
                                                     const ushort* __restrict__ p1,
                                                     const float* __restrict__ b1,
                                                     const ushort* __restrict__ p2,
                                                     const float* __restrict__ dinv,
                                                     ushort* __restrict__ Cb, int M) {
    __shared__ ushort la[64 * 128];   // A tile, 16KB (row-XOR swizzled)
    __shared__ ushort lh[64 * 256];   // h tile, 32KB (row-XOR swizzled)

    const int t = threadIdx.x;
    const int R0 = blockIdx.x * 64;
    const int w = t >> 6, l = t & 63;
    const int lrow = l & 15;
    const int lk = l >> 4;

    // ---- stage A tile: coalesced reads ----
    #pragma unroll
    for (int base = 0; base < 1024; base += 256) {
        int idx = base + t;
        int r = idx >> 4;
        int c8 = idx & 15;
        int gr = R0 + r;
        gr = gr < M ? gr : M - 1;                    // clamp (tail block)
        bf16x8 v = *(const bf16x8*)(A + (size_t)gr * 128 + c8 * 8);
        int byte = idx * 16 ^ ((r & 7) << 4);        // swizzled write
        *(bf16x8*)((char*)la + byte) = v;
    }

    // ---- hoist W1 fragments from packed p1 (overlaps A staging) ----
    bf16x8 w1[4][4];
    #pragma unroll
    for (int n = 0; n < 4; ++n)
        #pragma unroll
        for (int ks = 0; ks < 4; ++ks)
            w1[n][ks] = *(const bf16x8*)(p1 + (size_t)(((w * 4 + n) * 4 + ks) * 64 + l) * 8);
    __syncthreads();

    // ---- gemm1: LDS A + register W ----
    {
        const int c0 = w * 64;
        f32x4 acc[4][4] = {};
        #pragma unroll
        for (int ks = 0; ks < 4; ++ks) {
            bf16x8 xf[4];
            #pragma unroll
            for (int m = 0; m < 4; ++m) {
                int nd = m * 16 + lrow;
                int byte = (nd * 256 + ks * 64 + lk * 16) ^ ((nd & 7) << 4);
                xf[m] = *(const bf16x8*)((const char*)la + byte);
            }
            #pragma unroll
            for (int n = 0; n < 4; ++n)
                #pragma unroll
                for (int m = 0; m < 4; ++m)
                    acc[n][m] = __builtin_amdgcn_mfma_f32_16x16x32_bf16(w1[n][ks], xf[m], acc[n][m], 0, 0, 0);
        }
        // epilogue1: gelu(v+b1) -> packed 8B LDS stores
        #pragma unroll
        for (int n = 0; n < 4; ++n) {
            int ob = c0 + n * 16 + lk * 4;
            float4 bb = *(const float4*)(b1 + ob);
            #pragma unroll
            for (int m = 0; m < 4; ++m) {
                int nd = m * 16 + lrow;
                ushort4 pk;
                pk.x = f2bf(gelu_fast(acc[n][m][0] + bb.x));
                pk.y = f2bf(gelu_fast(acc[n][m][1] + bb.y));
                pk.z = f2bf(gelu_fast(acc[n][m][2] + bb.z));
                pk.w = f2bf(gelu_fast(acc[n][m][3] + bb.w));
                int byte = (nd * 256 + ob) * 2;
                byte ^= (nd & 7) << 4;
                *(ushort4*)((char*)lh + byte) = pk;
            }
        }
    }

    // ---- hoist W2 fragments from packed p2 ----
    bf16x8 w2[2][8];
    #pragma unroll
    for (int n = 0; n < 2; ++n)
        #pragma unroll
        for (int ks = 0; ks < 8; ++ks)
            w2[n][ks] = *(const bf16x8*)(p2 + (size_t)(((w * 2 + n) * 8 + ks) * 64 + l) * 8);
    __syncthreads();

    // ---- gemm2: LDS h + register W ----
    {
        const int c0 = w * 32;
        f32x4 acc2[2][4] = {};
        #pragma unroll
        for (int ks = 0; ks < 8; ++ks) {
            const int kb = ks * 32 + lk * 8;
            bf16x8 hf[4];
            #pragma unroll
            for (int m = 0; m < 4; ++m) {
                int nd = m * 16 + lrow;
                int byte = (nd * 256 + kb) * 2;
                byte ^= (nd & 7) << 4;
                hf[m] = *(const bf16x8*)((const char*)lh + byte);
            }
            #pragma unroll
            for (int n = 0; n < 2; ++n)
                #pragma unroll
                for (int m = 0; m < 4; ++m)
                    acc2[n][m] = __builtin_amdgcn_mfma_f32_16x16x32_bf16(w2[n][ks], hf[m], acc2[n][m], 0, 0, 0);
        }
        // epilogue2: dinv-scaled bf16, packed 8B global stores (in place)
        #pragma unroll
        for (int m = 0; m < 4; ++m) {
            int nd = m * 16 + lrow;
            int grow = R0 + nd;
            if (grow < M) {
                float sc = dinv[grow];
                #pragma unroll
                for (int n = 0; n < 2; ++n) {
                    int ob = c0 + n * 16 + lk * 4;
                    ushort4 pk;
                    pk.x = f2bf(acc2[n][m][0] * sc);
                    pk.y = f2bf(acc2[n][m][1] * sc);
                    pk.z = f2bf(acc2[n][m][2] * sc);
                    pk.w = f2bf(acc2[n][m][3] * sc);
                    *(ushort4*)(Cb + (size_t)grow * 128 + ob) = pk;
                }
            }
        }
    }
}

// ---------------- segment-sum gather, 16 edges in flight ----------------

template <bool BIAS, bool OUTBF>
__global__ __launch_bounds__(256) void gather_sum_kernel(const int* __restrict__ off,
                                                         const int* __restrict__ deg,
                                                         const int* __restrict__ rs,
                                                         const float* __restrict__ dinv,
                                                         const ushort* __restrict__ srcb,
                                                         const float* __restrict__ b,
                                                         float* __restrict__ dstf,
                                                         ushort* __restrict__ dstb, int M) {
    int wid = (blockIdx.x * 256 + threadIdx.x) >> 6;
    int lane = threadIdx.x & 63;
    int grp = lane >> 4;
    int l16 = lane & 15;
    if (wid >= M) return;
    int s0 = off[wid];
    int n = deg[wid];
    float acc[8] = {};
    float acc2[8] = {};

    if (grp == 0) {
        bf16x8 u = *(const bf16x8*)(srcb + (size_t)wid * 128 + l16 * 8);
        #pragma unroll
        for (int i = 0; i < 8; ++i) acc[i] += bf2f((ushort)u[i]);
    }

    int j = 0;
    for (; j + 16 <= n; j += 16) {
        int r0 = rs[s0 + j + grp];
        int r1 = rs[s0 + j + 4 + grp];
        int r2 = rs[s0 + j + 8 + grp];
        int r3 = rs[s0 + j + 12 + grp];
        bf16x8 u0 = *(const bf16x8*)(srcb + (size_t)r0 * 128 + l16 * 8);
        bf16x8 u1 = *(const bf16x8*)(srcb + (size_t)r1 * 128 + l16 * 8);
        bf16x8 u2 = *(const bf16x8*)(srcb + (size_t)r2 * 128 + l16 * 8);
        bf16x8 u3 = *(const bf16x8*)(srcb + (size_t)r3 * 128 + l16 * 8);
        #pragma unroll
        for (int i = 0; i < 8; ++i) {
            acc[i] += bf2f((ushort)u0[i]) + bf2f((ushort)u2[i]);
            acc2[i] += bf2f((ushort)u1[i]) + bf2f((ushort)u3[i]);
        }
    }
    for (; j + 4 <= n; j += 4) {
        int r = rs[s0 + j + grp];
        bf16x8 u = *(const bf16x8*)(srcb + (size_t)r * 128 + l16 * 8);
        #pragma unroll
        for (int i = 0; i < 8; ++i) acc[i] += bf2f((ushort)u[i]);
    }
    if (j + grp < n) {
        int r = rs[s0 + j + grp];
        bf16x8 u = *(const bf16x8*)(srcb + (size_t)r * 128 + l16 * 8);
        #pragma unroll
        for (int i = 0; i < 8; ++i) acc2[i] += bf2f((ushort)u[i]);
    }

    #pragma unroll
    for (int i = 0; i < 8; ++i) {
        acc[i] += acc2[i];
        acc[i] += __shfl_xor(acc[i], 16);
        acc[i] += __shfl_xor(acc[i], 32);
    }

    if (grp == 0) {
        float sc = dinv[wid];
        #pragma unroll
        for (int i = 0; i < 8; ++i) acc[i] *= sc;
        if constexpr (BIAS) {
            float4 b0 = *(const float4*)(b + l16 * 8);
            float4 b1v = *(const float4*)(b + l16 * 8 + 4);
            acc[0] += b0.x; acc[1] += b0.y; acc[2] += b0.z; acc[3] += b0.w;
            acc[4] += b1v.x; acc[5] += b1v.y; acc[6] += b1v.z; acc[7] += b1v.w;
        }
        if constexpr (OUTBF) {
            bf16x8 o;
            #pragma unroll
            for (int i = 0; i < 8; ++i) o[i] = (short)f2bf(acc[i]);
            *(bf16x8*)(dstb + (size_t)wid * 128 + l16 * 8) = o;
        } else {
            float4 o0 = make_float4(acc[0], acc[1], acc[2], acc[3]);
            float4 o1 = make_float4(acc[4], acc[5], acc[6], acc[7]);
            *(float4*)(dstf + (size_t)wid * 128 + l16 * 8) = o0;
            *(float4*)(dstf + (size_t)wid * 128 + l16 * 8 + 4) = o1;
        }
    }
}

// ---------------- launch ----------------

extern "C" void kernel_launch(void* const* d_in, const int* in_sizes, int n_in,
                              void* d_out, int out_size, void* d_ws, size_t ws_size,
                              hipStream_t stream) {
    const float* x  = (const float*)d_in[0];
    const int*   ei = (const int*)d_in[1];
    const float* W1 = (const float*)d_in[2];
    const float* b1 = (const float*)d_in[3];
    const float* W2 = (const float*)d_in[4];
    const float* b2 = (const float*)d_in[5];

    const int M = in_sizes[0] / 128;      // 100000
    const int E = in_sizes[1] / 2;        // 1600000
    const int* row = ei;
    const int* col = ei + E;

    // High-water ~73 MB.
    ushort* xb    = (ushort*)d_ws;              // 12,800,000 us (x*dinv, bf16)
    ushort* aggxb = xb + 12800000;              // 12,800,000 us [N,128]
    ushort* xw2b  = aggxb;                      // IN-PLACE alias (fused gemm same-row)
    float*  dinv  = (float*)(aggxb + 12800000); // 102,400 f
    int*    deg64 = (int*)(dinv + 102400);      // 1,638,400 i (64B-padded counters)
    int*    deg   = deg64 + 1638400;            // 102,400 i (compact, for scans)
    int*    off   = deg + 102400;               // 102,400 i
    int*    rank  = off + 102400;               // 1,600,000 i
    int*    rs    = rank + 1600000;             // 1,600,000 i
    int*    bsum  = rs + 1600000;               // 1,024 i
    ushort* p1    = (ushort*)(bsum + 1024);     // 32,768 us (W1 fragment-packed)
    ushort* p2    = p1 + 32768;                 // 32,768 us (W2 fragment-packed)
    float*  outw  = (float*)d_out;

    const int nb  = (M + 255) / 256;
    const int nbE = (E + 255) / 256;
    const int n8  = M * 16;

    hipMemsetAsync(deg64, 0, (size_t)1638400 * sizeof(int), stream);

    // pass 1: atomic histogram + rank, weight-pack riding the stall slots
    pass1_kernel<<<nbE + 32, 256, 0, stream>>>(col, deg64, rank, E, W1, W2, p1, p2);

    dinv_reduce_kernel<<<nb, 256, 0, stream>>>(deg64, dinv, deg, bsum, M);
    scan_bsum_kernel<<<1, 512, 0, stream>>>(bsum, nb);
    scan_offsets_kernel<<<nb, 256, 0, stream>>>(deg, bsum, off, M);

    // pass 2: CSR scatter + xb conversion riding the stall slots
    pass2_kernel<<<nbE + (n8 + 255) / 256, 256, 0, stream>>>(row, col, off, rank, rs, E,
                                                             x, dinv, xb, n8);

    // layer 1 aggregate (self from table), bf16 out
    gather_sum_kernel<false, true><<<(M * 64 + 255) / 256, 256, 0, stream>>>(
        off, deg, rs, dinv, xb, nullptr, nullptr, aggxb, M);

    // fused MLP: 64 rows/block, packed weights + LDS-staged A
    gemm_fused<<<(M + 63) / 64, 256, 0, stream>>>(aggxb, p1, b1, p2, dinv, xw2b, M);

    // layer 2 aggregate (self from table) + bias, fp32 out
    gather_sum_kernel<true, false><<<(M * 64 + 255) / 256, 256, 0, stream>>>(
        off, deg, rs, dinv, xw2b, b2, outw, nullptr, M);
}